// Round 20
// baseline (516.173 us; speedup 1.0000x reference)
//
#include <hip/hip_runtime.h>
#include <cmath>

#define B 8
#define N 1024
#define MSP 8
#define DIN 1024
#define HID 256
#define NLAYER 2
#define NCLS 7
#define NHEAD 4
#define DHD 64
#define G (B*NHEAD)   /* 32 */
#define SEQ 1024
#define GSEQ (G*SEQ)  /* 32768 */
#define LALPHA 0.1f
#define NEGF (-9e15f)
#define RROWS 8

typedef unsigned short u16;
typedef unsigned int u32;
typedef __attribute__((ext_vector_type(8))) short short8;
typedef __attribute__((ext_vector_type(4))) float f32x4;

__device__ __forceinline__ u16 f2bf(float f) {
  u32 u = __float_as_uint(f);
  u += 0x7FFFu + ((u >> 16) & 1u);   // RNE
  return (u16)(u >> 16);
}
__device__ __forceinline__ float bf2f(u16 v) {
  return __uint_as_float(((u32)v) << 16);
}
__device__ __forceinline__ void stf(float* p, size_t i, float v) { p[i] = v; }
__device__ __forceinline__ void stf(u16* p, size_t i, float v) { p[i] = f2bf(v); }

__device__ __forceinline__ float wave_reduce_sum(float v) {
  #pragma unroll
  for (int o = 32; o > 0; o >>= 1) v += __shfl_xor(v, o, 64);
  return v;
}
__device__ __forceinline__ float wave_reduce_max(float v) {
  #pragma unroll
  for (int o = 32; o > 0; o >>= 1) v = fmaxf(v, __shfl_xor(v, o, 64));
  return v;
}

// ---- 64x64 transpose-cast tile: src f32 [.,ldS] -> dst bf16 [.,ldD] --------
__device__ __forceinline__ void tcast_tile(
    const float* src, u16* dst, int ldS, int ldD, int r0, int c0, int t,
    u16* tile /* 64*72 */)
{
  #pragma unroll
  for (int i = 0; i < 4; ++i) {
    int e = i * 1024 + t * 4;
    int r = e >> 6, c = e & 63;
    float4 v = *(const float4*)&src[(size_t)(r0 + r) * ldS + c0 + c];
    u16* d = &tile[r * 72 + c];
    d[0] = f2bf(v.x); d[1] = f2bf(v.y); d[2] = f2bf(v.z); d[3] = f2bf(v.w);
  }
  __syncthreads();
  #pragma unroll
  for (int i = 0; i < 2; ++i) {
    int e = i * 2048 + t * 8;
    int r2 = e >> 6, c2 = e & 63;
    u16 v[8];
    #pragma unroll
    for (int j = 0; j < 8; ++j) v[j] = tile[(c2 + j) * 72 + r2];
    *(uint4*)&dst[(size_t)(c0 + r2) * ldD + r0 + c2] = *(const uint4*)v;
  }
}

// 22x 256x256 weights -> WT[z][256][256] bf16 transposed
__global__ __launch_bounds__(256) void wprep256(
    const float* g, const float* wv, const float* wk, const float* wq,
    const float* wo, const float* wz, const float* wr, const float* w,
    const float* uz, const float* ur, const float* u, u16* WT)
{
  __shared__ u16 tile[64 * 72];
  int z = blockIdx.z, idx = z >> 1, l = z & 1;
  const float* src;
  switch (idx) {
    case 0: src = g; break;  case 1: src = wv; break; case 2: src = wk; break;
    case 3: src = wq; break; case 4: src = wo; break; case 5: src = wz; break;
    case 6: src = wr; break; case 7: src = w; break;  case 8: src = uz; break;
    case 9: src = ur; break; default: src = u; break;
  }
  src += (size_t)l * 65536;
  u16* dst = WT + (size_t)z * 65536;
  tcast_tile(src, dst, 256, 256, blockIdx.x * 64, blockIdx.y * 64, threadIdx.x, tile);
}

// fc1_w / fc2_w [1024][256] -> WTfc[z][256][1024]
__global__ __launch_bounds__(256) void wprepfc(
    const float* w1, const float* w2, u16* WTfc)
{
  __shared__ u16 tile[64 * 72];
  int z = blockIdx.z;
  const float* src = z ? w2 : w1;
  u16* dst = WTfc + (size_t)z * 262144;
  tcast_tile(src, dst, 256, 1024, blockIdx.x * 64, blockIdx.y * 64, threadIdx.x, tile);
}

// generic u16 transpose: dst[c][r] = src[r][c], 64x64 tiles
__global__ __launch_bounds__(256) void utransp_kernel(
    const u16* __restrict__ src, u16* __restrict__ dst, int ldS, int ldD)
{
  __shared__ u16 tile[64 * 72];
  int r0 = blockIdx.x * 64, c0 = blockIdx.y * 64;
  int t = threadIdx.x;
  #pragma unroll
  for (int i = 0; i < 2; ++i) {
    int e = i * 256 + t;
    int sr = e >> 3, d8 = (e & 7) * 8;
    *(uint4*)&tile[sr * 72 + d8] = *(const uint4*)&src[(size_t)(r0 + sr) * ldS + c0 + d8];
  }
  __syncthreads();
  #pragma unroll
  for (int i = 0; i < 2; ++i) {
    int e = i * 256 + t;
    int dr = e >> 3, s8 = (e & 7) * 8;
    u16 v[8];
    #pragma unroll
    for (int j = 0; j < 8; ++j) v[j] = tile[(s8 + j) * 72 + dr];
    *(uint4*)&dst[(size_t)(c0 + dr) * ldD + r0 + s8] = *(const uint4*)v;
  }
}

// out_w [256][7] -> WTout [7][256]
__global__ __launch_bounds__(256) void outprep(const float* ow, u16* WTout) {
  int t = threadIdx.x;
  for (int e = t; e < NCLS * 256; e += 256) {
    int n = e >> 8, k = e & 255;
    WTout[e] = f2bf(ow[k * NCLS + n]);
  }
}

// ======================= universal MFMA GEMM (two z-groups) =================
__device__ __forceinline__ void stage_a(const float* p, u16* d) {
  #pragma unroll
  for (int q = 0; q < 4; ++q) {
    float4 v = *(const float4*)(p + q * 4);
    d[q * 4 + 0] = f2bf(v.x); d[q * 4 + 1] = f2bf(v.y);
    d[q * 4 + 2] = f2bf(v.z); d[q * 4 + 3] = f2bf(v.w);
  }
}
__device__ __forceinline__ void stage_a(const u16* p, u16* d) {
  *(uint4*)d = *(const uint4*)p;
  *(uint4*)(d + 8) = *(const uint4*)(p + 8);
}

// vtz >= 0: that z-index writes its output directly in Vt layout
// (Vt[(g*64+d)*SEQ + s], g=row>>8, s=(row&255)*4+(col>>6), d=col&63) to Cvt.
template <typename TA, typename TC>
__global__ __launch_bounds__(256) void gemm_t(
    const TA* __restrict__ A, const TA* __restrict__ A2, int zsplit,
    const u16* __restrict__ Wt, const u16* __restrict__ Wt2,
    const float* __restrict__ bias, const float* __restrict__ bias2,
    TC* __restrict__ C, u16* __restrict__ Cvt, int vtz,
    int K, int ldA, int ldW, int Nc, int act,
    size_t sA, size_t sW, size_t sC)
{
  __shared__ u16 As[64 * 72];
  __shared__ u16 Ws[64 * 72];
  int z = blockIdx.z;
  const TA* Ab; const u16* Wb; const float* bs;
  if (z < zsplit) {
    Ab = A + (size_t)z * sA; Wb = Wt + (size_t)z * sW; bs = bias;
  } else {
    int z2 = z - zsplit;
    Ab = A2 + (size_t)z2 * sA; Wb = Wt2 + (size_t)z2 * sW; bs = bias2;
  }
  TC* Cb = C + (size_t)z * sC;
  int bm = blockIdx.x * 64, bn = blockIdx.y * 64;
  int t = threadIdx.x;
  int w = t >> 6, lane = t & 63, quad = lane >> 4, l15 = lane & 15;
  int wy = w >> 1, wx = w & 1;
  int sr = t >> 2, kg = (t & 3) * 16;
  bool wok = (bn + sr) < Nc;
  f32x4 acc[2][2];
  #pragma unroll
  for (int i = 0; i < 2; ++i)
    #pragma unroll
    for (int j = 0; j < 2; ++j) acc[i][j] = (f32x4){0.f, 0.f, 0.f, 0.f};

  for (int k0 = 0; k0 < K; k0 += 64) {
    u16 av[16];
    stage_a(Ab + (size_t)(bm + sr) * ldA + k0 + kg, av);
    *(uint4*)&As[sr * 72 + kg] = *(const uint4*)av;
    *(uint4*)&As[sr * 72 + kg + 8] = *(const uint4*)(av + 8);
    if (wok) {
      *(uint4*)&Ws[sr * 72 + kg] = *(const uint4*)(Wb + (size_t)(bn + sr) * ldW + k0 + kg);
      *(uint4*)&Ws[sr * 72 + kg + 8] = *(const uint4*)(Wb + (size_t)(bn + sr) * ldW + k0 + kg + 8);
    } else {
      uint4 zz = {0, 0, 0, 0};
      *(uint4*)&Ws[sr * 72 + kg] = zz;
      *(uint4*)&Ws[sr * 72 + kg + 8] = zz;
    }
    __syncthreads();
    #pragma unroll
    for (int kh = 0; kh < 64; kh += 32) {
      short8 a0 = *(const short8*)&As[(wy * 32 + l15) * 72 + kh + quad * 8];
      short8 a1 = *(const short8*)&As[(wy * 32 + 16 + l15) * 72 + kh + quad * 8];
      short8 b0 = *(const short8*)&Ws[(wx * 32 + l15) * 72 + kh + quad * 8];
      short8 b1 = *(const short8*)&Ws[(wx * 32 + 16 + l15) * 72 + kh + quad * 8];
      acc[0][0] = __builtin_amdgcn_mfma_f32_16x16x32_bf16(a0, b0, acc[0][0], 0, 0, 0);
      acc[0][1] = __builtin_amdgcn_mfma_f32_16x16x32_bf16(a0, b1, acc[0][1], 0, 0, 0);
      acc[1][0] = __builtin_amdgcn_mfma_f32_16x16x32_bf16(a1, b0, acc[1][0], 0, 0, 0);
      acc[1][1] = __builtin_amdgcn_mfma_f32_16x16x32_bf16(a1, b1, acc[1][1], 0, 0, 0);
    }
    __syncthreads();
  }
  if (z == vtz) {
    // V output directly in Vt layout (replaces vtransp kernel)
    #pragma unroll
    for (int sa = 0; sa < 2; ++sa) {
      #pragma unroll
      for (int sb = 0; sb < 2; ++sb) {
        int col = bn + wx * 32 + sb * 16 + l15;
        float bv = bs ? bs[col] : 0.f;
        int gi64 = 0;  // computed per row below
        #pragma unroll
        for (int r = 0; r < 4; ++r) {
          int row = bm + wy * 32 + sa * 16 + quad * 4 + r;
          float v = acc[sa][sb][r] + bv;
          int gI = row >> 8, sI = ((row & 255) << 2) + (col >> 6), dI = col & 63;
          Cvt[((size_t)(gI * 64 + dI)) * SEQ + sI] = f2bf(v);
          (void)gi64;
        }
      }
    }
    return;
  }
  #pragma unroll
  for (int sa = 0; sa < 2; ++sa) {
    #pragma unroll
    for (int sb = 0; sb < 2; ++sb) {
      int col = bn + wx * 32 + sb * 16 + l15;
      if (col < Nc) {
        float bv = bs ? bs[col] : 0.f;
        #pragma unroll
        for (int r = 0; r < 4; ++r) {
          int row = bm + wy * 32 + sa * 16 + quad * 4 + r;
          float v = acc[sa][sb][r] + bv;
          if (act == 1) v = fmaxf(v, 0.f);
          else if (act == 2) v = (v > 0.f) ? v : (__expf(v) - 1.f);  // elu
          stf(Cb, (size_t)row * Nc + col, v);
        }
      }
    }
  }
}

// ---- fused wo-GEMM + LayerNorm: Hn = LN(A@wo + bo + Hres) ------------------
__global__ __launch_bounds__(256) void wo_ln_kernel(
    const float* __restrict__ A, const u16* __restrict__ Wt,
    const float* __restrict__ bias, const float* __restrict__ Hres,
    const float* __restrict__ gg, const float* __restrict__ bb,
    float* __restrict__ out)
{
  __shared__ u16 As[32 * 72];
  __shared__ u16 Ws[256 * 72];
  __shared__ float red1[2][32], red2[2][32];
  int bm = blockIdx.x * 32;
  int t = threadIdx.x;
  int w = t >> 6, lane = t & 63, quad = lane >> 4, l15 = lane & 15;
  int rhalf = w & 1, chalf = w >> 1;
  f32x4 acc[8];
  #pragma unroll
  for (int nt = 0; nt < 8; ++nt) acc[nt] = (f32x4){0.f, 0.f, 0.f, 0.f};

  for (int k0 = 0; k0 < HID; k0 += 64) {
    {
      int row = t >> 3, k8 = (t & 7) * 8;
      const float* p = A + (size_t)(bm + row) * HID + k0 + k8;
      float4 v0 = *(const float4*)p;
      float4 v1 = *(const float4*)(p + 4);
      u16 d[8];
      d[0] = f2bf(v0.x); d[1] = f2bf(v0.y); d[2] = f2bf(v0.z); d[3] = f2bf(v0.w);
      d[4] = f2bf(v1.x); d[5] = f2bf(v1.y); d[6] = f2bf(v1.z); d[7] = f2bf(v1.w);
      *(uint4*)&As[row * 72 + k8] = *(const uint4*)d;
    }
    #pragma unroll
    for (int i = 0; i < 8; ++i) {
      int e = i * 256 + t;
      int n = e >> 3, k8 = (e & 7) * 8;
      *(uint4*)&Ws[n * 72 + k8] = *(const uint4*)&Wt[(size_t)n * HID + k0 + k8];
    }
    __syncthreads();
    #pragma unroll
    for (int kh = 0; kh < 64; kh += 32) {
      short8 a = *(const short8*)&As[(rhalf * 16 + l15) * 72 + kh + quad * 8];
      #pragma unroll
      for (int nt = 0; nt < 8; ++nt) {
        short8 b = *(const short8*)&Ws[(chalf * 128 + nt * 16 + l15) * 72 + kh + quad * 8];
        acc[nt] = __builtin_amdgcn_mfma_f32_16x16x32_bf16(a, b, acc[nt], 0, 0, 0);
      }
    }
    __syncthreads();
  }
  float rs1[4] = {0, 0, 0, 0}, rs2[4] = {0, 0, 0, 0};
  #pragma unroll
  for (int nt = 0; nt < 8; ++nt) {
    int col = chalf * 128 + nt * 16 + l15;
    float bv = bias[col];
    #pragma unroll
    for (int r = 0; r < 4; ++r) {
      int row = bm + rhalf * 16 + quad * 4 + r;
      float v = acc[nt][r] + bv + Hres[(size_t)row * HID + col];
      acc[nt][r] = v;
      rs1[r] += v;
      rs2[r] += v * v;
    }
  }
  #pragma unroll
  for (int off = 1; off < 16; off <<= 1) {
    #pragma unroll
    for (int r = 0; r < 4; ++r) {
      rs1[r] += __shfl_xor(rs1[r], off, 64);
      rs2[r] += __shfl_xor(rs2[r], off, 64);
    }
  }
  if (l15 == 0) {
    #pragma unroll
    for (int r = 0; r < 4; ++r) {
      red1[chalf][rhalf * 16 + quad * 4 + r] = rs1[r];
      red2[chalf][rhalf * 16 + quad * 4 + r] = rs2[r];
    }
  }
  __syncthreads();
  float mu[4], rstd[4];
  #pragma unroll
  for (int r = 0; r < 4; ++r) {
    int lr = rhalf * 16 + quad * 4 + r;
    float s1 = red1[0][lr] + red1[1][lr];
    float s2 = red2[0][lr] + red2[1][lr];
    float m = s1 * (1.f / HID);
    float var = s2 * (1.f / HID) - m * m;
    var = fmaxf(var, 0.f);
    mu[r] = m;
    rstd[r] = rsqrtf(var + 1e-5f);
  }
  #pragma unroll
  for (int nt = 0; nt < 8; ++nt) {
    int col = chalf * 128 + nt * 16 + l15;
    float g = gg[col], bbv = bb[col];
    #pragma unroll
    for (int r = 0; r < 4; ++r) {
      int row = bm + rhalf * 16 + quad * 4 + r;
      out[(size_t)row * HID + col] = (acc[nt][r] - mu[r]) * rstd[r] * g + bbv;
    }
  }
}

// -------- fc2 K-split reduce ------------------------------------------------
__global__ __launch_bounds__(256) void fc2_reduce(
    const float* __restrict__ scr, const float* __restrict__ bias,
    float* __restrict__ out)
{
  int i = blockIdx.x * 256 + threadIdx.x;
  float v = scr[i] + scr[16384 + i] + scr[32768 + i] + scr[49152 + i]
          + bias[threadIdx.x];
  out[i] = fmaxf(v, 0.f);
}

// -------- GRU combine -------------------------------------------------------
__global__ __launch_bounds__(256) void gru_combine(
    const float* __restrict__ zP, const float* __restrict__ zU,
    const float* __restrict__ P, float* __restrict__ Pn)
{
  int i = blockIdx.x * 256 + threadIdx.x;
  float z = 1.f / (1.f + __expf(-(zP[i] + zU[i])));
  float r = 1.f / (1.f + __expf(-(zP[16384 + i] + zU[16384 + i])));
  float hh = tanhf(zP[32768 + i] + r * zU[32768 + i]);
  Pn[i] = (1.f - z) * P[i] + z * hh;
}

// -------- P_l_1 batched: 8 n-rows/block, 32 lanes x 8 d per row -------------
__global__ __launch_bounds__(256) void pl1_kernel(
    const float* __restrict__ s_adj, const float* __restrict__ P,
    float* __restrict__ out)
{
  int blk = blockIdx.x;             // B*N/8 = 1024
  int b = blk >> 7;
  int n = ((blk & 127) << 3) + (threadIdx.x >> 5);
  int d0 = (threadIdx.x & 31) * 8;
  float acc[8] = {};
  #pragma unroll
  for (int m = 0; m < MSP; ++m) {
    float sa = s_adj[(size_t)(b * MSP + m) * N + n];
    const float* Pp = &P[(size_t)(b * MSP + m) * HID + d0];
    float4 p0 = *(const float4*)Pp;
    float4 p1 = *(const float4*)(Pp + 4);
    acc[0] += sa * p0.x; acc[1] += sa * p0.y; acc[2] += sa * p0.z; acc[3] += sa * p0.w;
    acc[4] += sa * p1.x; acc[5] += sa * p1.y; acc[6] += sa * p1.z; acc[7] += sa * p1.w;
  }
  float* op = &out[(size_t)(b * N + n) * HID + d0];
  *(float4*)op = (float4){acc[0], acc[1], acc[2], acc[3]};
  *(float4*)(op + 4) = (float4){acc[4], acc[5], acc[6], acc[7]};
}

// -------- rel_sc (both layers, once) ----------------------------------------
__global__ __launch_bounds__(256) void relsc_kernel(
    const float* __restrict__ rel_emb, const float* __restrict__ gat_a,
    float* __restrict__ rsc)
{
  __shared__ float scratch[4];
  int z = blockIdx.x, l = z >> 1, r = z & 1, t = threadIdx.x;
  const float* re = rel_emb + ((size_t)l * 2 + r) * HID;
  const float* a3 = gat_a + (size_t)l * 3 * HID + 2 * HID;
  float v = re[t] * a3[t];
  int wave = t >> 6, lane = t & 63;
  v = wave_reduce_sum(v);
  if (lane == 0) scratch[wave] = v;
  __syncthreads();
  if (t == 0) rsc[z] = scratch[0] + scratch[1] + scratch[2] + scratch[3];
}

// -------- f1/f2 batched: 8 rows/block ---------------------------------------
__global__ __launch_bounds__(256) void f1f2_kernel(
    const u16* __restrict__ h, const float* __restrict__ a12,
    float* __restrict__ f1, float* __restrict__ f2)
{
  int row0 = blockIdx.x * 8;
  int t = threadIdx.x;
  int r = t >> 5;
  int c0 = (t & 31) * 8;
  const u16* hp = &h[(size_t)(row0 + r) * HID + c0];
  uint4 raw = *(const uint4*)hp;
  const u16* hv16 = (const u16*)&raw;
  float v1 = 0.f, v2 = 0.f;
  #pragma unroll
  for (int j = 0; j < 8; ++j) {
    float hv = bf2f(hv16[j]);
    v1 += hv * a12[c0 + j];
    v2 += hv * a12[HID + c0 + j];
  }
  #pragma unroll
  for (int off = 1; off < 32; off <<= 1) {
    v1 += __shfl_xor(v1, off, 32);
    v2 += __shfl_xor(v2, off, 32);
  }
  if ((t & 31) == 0) {
    f1[row0 + r] = v1;
    f2[row0 + r] = v2;
  }
}

// -------- RGAT scores (register-resident) -----------------------------------
__global__ __launch_bounds__(256) void rgat_scores_kernel(
    const int* __restrict__ adj, const int* __restrict__ smask,
    const float* __restrict__ f1, const float* __restrict__ f2,
    const float* __restrict__ rsc, u16* __restrict__ Pw)
{
  __shared__ float red[4][RROWS];
  int blk = blockIdx.x;
  int b = blk / (N / RROWS);
  int i0 = (blk % (N / RROWS)) * RROWS;
  int t = threadIdx.x;
  int wave = t >> 6, lane = t & 63;
  float r0 = rsc[0], r1 = rsc[1];
  int j0 = t * 4;
  float4 f2v = *(const float4*)&f2[b * N + j0];
  float ev[RROWS][4];
  #pragma unroll
  for (int r = 0; r < RROWS; ++r) {
    size_t base = ((size_t)(b * N + i0 + r)) * N + j0;
    int4 a4 = *(const int4*)&adj[base];
    int4 s4 = *(const int4*)&smask[base];
    float f1v = f1[b * N + i0 + r];
    float e;
    e = f1v + f2v.x + (s4.x ? r1 : r0); e = (e > 0.f) ? e : LALPHA * e;
    ev[r][0] = (a4.x > 0) ? e : NEGF;
    e = f1v + f2v.y + (s4.y ? r1 : r0); e = (e > 0.f) ? e : LALPHA * e;
    ev[r][1] = (a4.y > 0) ? e : NEGF;
    e = f1v + f2v.z + (s4.z ? r1 : r0); e = (e > 0.f) ? e : LALPHA * e;
    ev[r][2] = (a4.z > 0) ? e : NEGF;
    e = f1v + f2v.w + (s4.w ? r1 : r0); e = (e > 0.f) ? e : LALPHA * e;
    ev[r][3] = (a4.w > 0) ? e : NEGF;
  }
  #pragma unroll
  for (int r = 0; r < RROWS; ++r) {
    float m = fmaxf(fmaxf(ev[r][0], ev[r][1]), fmaxf(ev[r][2], ev[r][3]));
    m = wave_reduce_max(m);
    if (lane == 0) red[wave][r] = m;
  }
  __syncthreads();
  float mx[RROWS];
  #pragma unroll
  for (int r = 0; r < RROWS; ++r)
    mx[r] = fmaxf(fmaxf(red[0][r], red[1][r]), fmaxf(red[2][r], red[3][r]));
  __syncthreads();
  #pragma unroll
  for (int r = 0; r < RROWS; ++r) {
    float s = 0.f;
    #pragma unroll
    for (int c = 0; c < 4; ++c) { ev[r][c] = __expf(ev[r][c] - mx[r]); s += ev[r][c]; }
    s = wave_reduce_sum(s);
    if (lane == 0) red[wave][r] = s;
  }
  __syncthreads();
  #pragma unroll
  for (int r = 0; r < RROWS; ++r) {
    float inv = 1.f / (red[0][r] + red[1][r] + red[2][r] + red[3][r]);
    u16 o[4];
    #pragma unroll
    for (int c = 0; c < 4; ++c) o[c] = f2bf(ev[r][c] * inv);
    *(uint2*)&Pw[((size_t)(b * N + i0 + r)) * N + j0] = *(const uint2*)o;
  }
}

// -------- MFMA flash MHA: 64-key chunks, XCD swizzle, LDS double-buffer -----
__global__ __launch_bounds__(256) void mha_mfma_kernel(
    const u16* __restrict__ Qb, const u16* __restrict__ Kb,
    const u16* __restrict__ Vt, float* __restrict__ ctx)
{
  __shared__ u16 Ks[2][64 * 72];
  __shared__ u16 Vs[2][64 * 72];
  __shared__ u16 Ps[4][16 * 72];
  int g = blockIdx.x & 31;
  int q0 = (blockIdx.x >> 5) * 64;
  int t = threadIdx.x;
  int w = t >> 6, lane = t & 63, quad = lane >> 4, l15 = lane & 15;
  const u16* Qrow = Qb + ((size_t)(g * SEQ) + q0 + w * 16 + l15) * DHD;
  short8 qa0 = *(const short8*)(Qrow + quad * 8);
  short8 qa1 = *(const short8*)(Qrow + 32 + quad * 8);
  const u16* Kg = Kb + (size_t)g * SEQ * DHD;
  const u16* Vg = Vt + (size_t)g * DHD * SEQ;
  int srow = t >> 3, sc8 = (t & 7) * 8;
  int srow1 = (256 + t) >> 3;
  f32x4 O[4];
  #pragma unroll
  for (int nt = 0; nt < 4; ++nt) O[nt] = (f32x4){0.f, 0.f, 0.f, 0.f};
  float mprev[4] = {-1e30f, -1e30f, -1e30f, -1e30f};
  float lsum[4] = {0.f, 0.f, 0.f, 0.f};

  *(uint4*)&Ks[0][srow * 72 + sc8] = *(const uint4*)&Kg[(size_t)srow * DHD + sc8];
  *(uint4*)&Ks[0][srow1 * 72 + sc8] = *(const uint4*)&Kg[(size_t)srow1 * DHD + sc8];
  *(uint4*)&Vs[0][srow * 72 + sc8] = *(const uint4*)&Vg[(size_t)srow * SEQ + sc8];
  *(uint4*)&Vs[0][srow1 * 72 + sc8] = *(const uint4*)&Vg[(size_t)srow1 * SEQ + sc8];

  int ping = 0;
  for (int kc = 0; kc < SEQ; kc += 64) {
    __syncthreads();
    if (kc + 64 < SEQ) {
      int pn = 1 - ping, kn = kc + 64;
      *(uint4*)&Ks[pn][srow * 72 + sc8] = *(const uint4*)&Kg[(size_t)(kn + srow) * DHD + sc8];
      *(uint4*)&Ks[pn][srow1 * 72 + sc8] = *(const uint4*)&Kg[(size_t)(kn + srow1) * DHD + sc8];
      *(uint4*)&Vs[pn][srow * 72 + sc8] = *(const uint4*)&Vg[(size_t)srow * SEQ + kn + sc8];
      *(uint4*)&Vs[pn][srow1 * 72 + sc8] = *(const uint4*)&Vg[(size_t)srow1 * SEQ + kn + sc8];
    }
    f32x4 s[4];
    #pragma unroll
    for (int st = 0; st < 4; ++st) {
      short8 b0 = *(const short8*)&Ks[ping][(st * 16 + l15) * 72 + quad * 8];
      short8 b1 = *(const short8*)&Ks[ping][(st * 16 + l15) * 72 + 32 + quad * 8];
      f32x4 c = (f32x4){0.f, 0.f, 0.f, 0.f};
      c = __builtin_amdgcn_mfma_f32_16x16x32_bf16(qa0, b0, c, 0, 0, 0);
      c = __builtin_amdgcn_mfma_f32_16x16x32_bf16(qa1, b1, c, 0, 0, 0);
      s[st] = c * 0.125f;
    }
    float cm[4];
    #pragma unroll
    for (int r = 0; r < 4; ++r)
      cm[r] = fmaxf(fmaxf(s[0][r], s[1][r]), fmaxf(s[2][r], s[3][r]));
    #pragma unroll
    for (int off = 1; off < 16; off <<= 1) {
      #pragma unroll
      for (int r = 0; r < 4; ++r) cm[r] = fmaxf(cm[r], __shfl_xor(cm[r], off, 64));
    }
    float mnew[4], alpha[4], rs[4];
    #pragma unroll
    for (int r = 0; r < 4; ++r) {
      mnew[r] = fmaxf(mprev[r], cm[r]);
      alpha[r] = __expf(mprev[r] - mnew[r]);
      mprev[r] = mnew[r];
      rs[r] = 0.f;
    }
    #pragma unroll
    for (int st = 0; st < 4; ++st) {
      #pragma unroll
      for (int r = 0; r < 4; ++r) {
        float p = __expf(s[st][r] - mnew[r]);
        rs[r] += p;
        Ps[w][(quad * 4 + r) * 72 + st * 16 + l15] = f2bf(p);
      }
    }
    #pragma unroll
    for (int off = 1; off < 16; off <<= 1) {
      #pragma unroll
      for (int r = 0; r < 4; ++r) rs[r] += __shfl_xor(rs[r], off, 64);
    }
    #pragma unroll
    for (int r = 0; r < 4; ++r) lsum[r] = lsum[r] * alpha[r] + rs[r];
    #pragma unroll
    for (int nt = 0; nt < 4; ++nt)
      #pragma unroll
      for (int r = 0; r < 4; ++r) O[nt][r] *= alpha[r];
    #pragma unroll
    for (int kh = 0; kh < 2; ++kh) {
      short8 pa = *(const short8*)&Ps[w][l15 * 72 + kh * 32 + quad * 8];
      #pragma unroll
      for (int nt = 0; nt < 4; ++nt) {
        short8 vb = *(const short8*)&Vs[ping][(nt * 16 + l15) * 72 + kh * 32 + quad * 8];
        O[nt] = __builtin_amdgcn_mfma_f32_16x16x32_bf16(pa, vb, O[nt], 0, 0, 0);
      }
    }
    ping ^= 1;
  }
  #pragma unroll
  for (int nt = 0; nt < 4; ++nt) {
    #pragma unroll
    for (int r = 0; r < 4; ++r) {
      size_t row = (size_t)(g * SEQ) + q0 + w * 16 + quad * 4 + r;
      ctx[row * DHD + nt * 16 + l15] = O[nt][r] / lsum[r];
    }
  }
}

// -------- P_agg split-n: part + reduce --------------------------------------
__global__ __launch_bounds__(256) void pagg_part(
    const float* __restrict__ s_adj, const float* __restrict__ H,
    float* __restrict__ scr)
{
  int row = blockIdx.x;
  int sl = blockIdx.y;
  int b = row >> 3, t = threadIdx.x;
  const float* Hb = H + ((size_t)(b * N) + sl * 128) * HID + t;
  const float* sa = s_adj + (size_t)row * N + sl * 128;
  float acc = 0.f;
  #pragma unroll 4
  for (int n = 0; n < 128; ++n)
    acc += sa[n] * Hb[(size_t)n * HID];
  scr[((size_t)sl * (B * MSP) + row) * HID + t] = acc;
}
__global__ __launch_bounds__(256) void pagg_reduce(
    const float* __restrict__ scr, float* __restrict__ Pagg)
{
  int row = blockIdx.x, t = threadIdx.x;
  float s = 0.f;
  #pragma unroll
  for (int k = 0; k < 8; ++k) s += scr[((size_t)k * (B * MSP) + row) * HID + t];
  Pagg[(size_t)row * HID + t] = s;
}

// -------- p_sim -------------------------------------------------------------
__global__ __launch_bounds__(256) void psim_kernel(
    const float* __restrict__ P, float* __restrict__ out)
{
  __shared__ float scratch[4];
  int t = threadIdx.x;
  float total = 0.f;
  for (int idx = t; idx < B * MSP * MSP; idx += 256) {
    int b = idx >> 6, m = (idx >> 3) & 7, k = idx & 7;
    if (m != k) {
      const float* pm = P + (size_t)(b * MSP + m) * HID;
      const float* pk = P + (size_t)(b * MSP + k) * HID;
      float d = 0.f;
      for (int dd = 0; dd < HID; ++dd) d += pm[dd] * pk[dd];
      total += d;
    }
  }
  int wave = t >> 6, lane = t & 63;
  total = wave_reduce_sum(total);
  if (lane == 0) scratch[wave] = total;
  __syncthreads();
  if (t == 0)
    out[0] = (scratch[0] + scratch[1] + scratch[2] + scratch[3]) *
             (1.f / (B * MSP * MSP));
}

extern "C" void kernel_launch(void* const* d_in, const int* in_sizes, int n_in,
                              void* d_out, int out_size, void* d_ws, size_t ws_size,
                              hipStream_t stream) {
  const float* x      = (const float*)d_in[0];
  const int*   adj    = (const int*)d_in[1];
  const int*   smask  = (const int*)d_in[2];
  const float* s_feat = (const float*)d_in[3];
  const float* s_adj  = (const float*)d_in[4];
  const float* fc1_w  = (const float*)d_in[6];
  const float* fc1_b  = (const float*)d_in[7];
  const float* fc2_w  = (const float*)d_in[8];
  const float* fc2_b  = (const float*)d_in[9];
  const float* gat_W  = (const float*)d_in[10];
  const float* gat_a  = (const float*)d_in[11];
  const float* rel_emb= (const float*)d_in[12];
  const float* gru_wz = (const float*)d_in[13];
  const float* gru_uz = (const float*)d_in[14];
  const float* gru_wr = (const float*)d_in[15];
  const float* gru_ur = (const float*)d_in[16];
  const float* gru_w  = (const float*)d_in[17];
  const float* gru_u  = (const float*)d_in[18];
  const float* mha_wv = (const float*)d_in[19];
  const float* mha_bv = (const float*)d_in[20];
  const float* mha_wk = (const float*)d_in[21];
  const float* mha_bk = (const float*)d_in[22];
  const float* mha_wq = (const float*)d_in[23];
  const float* mha_bq = (const float*)d_in[24];
  const float* mha_wo = (const float*)d_in[25];
  const float* mha_bo = (const float*)d_in[26];
  const float* ln_g   = (const float*)d_in[27];
  const float* ln_b   = (const float*)d_in[28];
  const float* out_w  = (const float*)d_in[29];
  const float* out_b  = (const float*)d_in[30];

  float* ws = (float*)d_ws;
  const size_t BIG = (size_t)B * N * HID;   // 2,097,152 floats (8 MB)
  float* H0  = ws + 0 * BIG;
  float* H1  = ws + 1 * BIG;
  u16* hb16 = (u16*)(ws + 2 * BIG);
  u16* Vt16 = hb16 + BIG;             // V written directly transposed here
  float* Pl1 = ws + 3 * BIG;
  float* Agg = ws + 4 * BIG;
  u16* Pw   = (u16*)(ws + 5 * BIG);   // slots 5+6 (16 MB)
  u16* Qb16 = (u16*)(ws + 5 * BIG);   // valid only after Pw consumed
  u16* Kb16 = Qb16 + BIG;
  u16* ht   = (u16*)(ws + 7 * BIG);
  u16* WT   = ht + 2097152;
  u16* WTfc = WT + 22 * 65536;
  u16* WTout= WTfc + 2 * 262144;
  float* scrFc = Agg;
  float* zP = Pl1;
  float* zU = Pl1 + 3 * 16384;
  float* paggScr = Pl1 + 6 * 16384;
  float* smw = ws + 8 * BIG;
  float* P0   = smw;
  float* P1   = smw + 16384;
  float* Pagg = smw + 32768;
  float* f1   = smw + 49152;
  float* f2   = smw + 57344;
  float* rsc4 = smw + 65536;

  dim3 blk(256);
  const size_t W64K = 65536;

  wprep256<<<dim3(4, 4, 22), blk, 0, stream>>>(
      gat_W, mha_wv, mha_wk, mha_wq, mha_wo,
      gru_wz, gru_wr, gru_w, gru_uz, gru_ur, gru_u, WT);
  wprepfc<<<dim3(16, 4, 2), blk, 0, stream>>>(fc1_w, fc2_w, WTfc);
  outprep<<<1, blk, 0, stream>>>(out_w, WTout);
  relsc_kernel<<<4, blk, 0, stream>>>(rel_emb, gat_a, rsc4);

  gemm_t<float, float><<<dim3(128, 4, 1), blk, 0, stream>>>(
      x, x, 99, WTfc, WTfc, fc1_b, fc1_b, H0, nullptr, -1,
      DIN, DIN, DIN, HID, 1, 0, 0, 0);
  gemm_t<float, float><<<dim3(1, 4, 4), blk, 0, stream>>>(
      s_feat, s_feat, 99, WTfc + 262144, WTfc, nullptr, nullptr, scrFc, nullptr, -1,
      256, DIN, DIN, HID, 0, 256, 256, 16384);
  fc2_reduce<<<64, blk, 0, stream>>>(scrFc, fc2_b, P0);

  float* Hc = H0; float* Hn = H1; float* Pc = P0; float* Pn = P1;
  for (int l = 0; l < NLAYER; ++l) {
    pl1_kernel<<<B * N / 8, blk, 0, stream>>>(s_adj, Pc, Pl1);
    // z=0: h -> hb16 (row-major). z=1: V -> Vt16 directly transposed.
    gemm_t<float, u16><<<dim3(128, 4, 2), blk, 0, stream>>>(
        Hc, Hc, 1, WT + (size_t)(0 + l) * W64K, WT + (size_t)(2 + l) * W64K,
        nullptr, mha_bv + l * HID, hb16, Vt16, 1,
        HID, HID, HID, HID, 0, 0, 0, 0);
    utransp_kernel<<<dim3(128, 4), blk, 0, stream>>>(hb16, ht, HID, B * N);
    f1f2_kernel<<<B * N / 8, blk, 0, stream>>>(hb16, gat_a + (size_t)l * 3 * HID, f1, f2);
    rgat_scores_kernel<<<B * (N / RROWS), blk, 0, stream>>>(adj, smask, f1, f2,
                                                           rsc4 + l * 2, Pw);
    gemm_t<u16, float><<<dim3(16, 4, 8), blk, 0, stream>>>(
        Pw, Pw, 99, ht, ht, nullptr, nullptr, Agg, nullptr, -1,
        N, N, B * N, HID, 2,
        (size_t)N * N, (size_t)N, (size_t)N * HID);
    gemm_t<float, u16><<<dim3(128, 4, 2), blk, 0, stream>>>(
        Agg, Pl1, 1, WT + (size_t)(6 + l) * W64K, WT + (size_t)(4 + l) * W64K,
        mha_bq + l * HID, mha_bk + l * HID, Qb16, nullptr, -1,
        HID, HID, HID, HID, 0, 0, 0, BIG);
    mha_mfma_kernel<<<G * (SEQ / 64), blk, 0, stream>>>(Qb16, Kb16, Vt16, Agg);
    wo_ln_kernel<<<B * N / 32, blk, 0, stream>>>(
        Agg, WT + (size_t)(8 + l) * W64K, mha_bo + l * HID, Hc,
        ln_g + l * HID, ln_b + l * HID, Hn);
    pagg_part<<<dim3(B * MSP, 8), blk, 0, stream>>>(s_adj, Hc, paggScr);
    pagg_reduce<<<B * MSP, blk, 0, stream>>>(paggScr, Pagg);
    gemm_t<float, float><<<dim3(1, 4, 6), blk, 0, stream>>>(
        Pc, Pagg, 3, WT + (size_t)(10 + l) * W64K, WT + (size_t)(16 + l) * W64K,
        nullptr, nullptr, zP, nullptr, -1,
        HID, HID, HID, HID, 0, 0, 2 * W64K, 16384);
    gru_combine<<<64, blk, 0, stream>>>(zP, zU, Pc, Pn);
    float* th = Hc; Hc = Hn; Hn = th;
    float* tp = Pc; Pc = Pn; Pn = tp;
  }
  gemm_t<float, float><<<dim3(128, 1, 1), blk, 0, stream>>>(
      Hc, Hc, 99, WTout, WTout, out_b, out_b, (float*)d_out, nullptr, -1,
      HID, HID, HID, NCLS, 0, 0, 0, 0);
  psim_kernel<<<1, blk, 0, stream>>>(Pc, (float*)d_out + (size_t)B * N * NCLS);
}

// Round 21
// 511.169 us; speedup vs baseline: 1.0098x; 1.0098x over previous
//
#include <hip/hip_runtime.h>
#include <cmath>

#define B 8
#define N 1024
#define MSP 8
#define DIN 1024
#define HID 256
#define NLAYER 2
#define NCLS 7
#define NHEAD 4
#define DHD 64
#define G (B*NHEAD)   /* 32 */
#define SEQ 1024
#define GSEQ (G*SEQ)  /* 32768 */
#define LALPHA 0.1f
#define NEGF (-9e15f)
#define RROWS 8

typedef unsigned short u16;
typedef unsigned int u32;
typedef __attribute__((ext_vector_type(8))) short short8;
typedef __attribute__((ext_vector_type(4))) float f32x4;

__device__ __forceinline__ u16 f2bf(float f) {
  u32 u = __float_as_uint(f);
  u += 0x7FFFu + ((u >> 16) & 1u);   // RNE
  return (u16)(u >> 16);
}
__device__ __forceinline__ float bf2f(u16 v) {
  return __uint_as_float(((u32)v) << 16);
}
__device__ __forceinline__ void stf(float* p, size_t i, float v) { p[i] = v; }
__device__ __forceinline__ void stf(u16* p, size_t i, float v) { p[i] = f2bf(v); }

__device__ __forceinline__ float wave_reduce_sum(float v) {
  #pragma unroll
  for (int o = 32; o > 0; o >>= 1) v += __shfl_xor(v, o, 64);
  return v;
}
__device__ __forceinline__ float wave_reduce_max(float v) {
  #pragma unroll
  for (int o = 32; o > 0; o >>= 1) v = fmaxf(v, __shfl_xor(v, o, 64));
  return v;
}

// ---- 64x64 transpose-cast tile: src f32 [.,ldS] -> dst bf16 [.,ldD] --------
__device__ __forceinline__ void tcast_tile(
    const float* src, u16* dst, int ldS, int ldD, int r0, int c0, int t,
    u16* tile /* 64*72 */)
{
  #pragma unroll
  for (int i = 0; i < 4; ++i) {
    int e = i * 1024 + t * 4;
    int r = e >> 6, c = e & 63;
    float4 v = *(const float4*)&src[(size_t)(r0 + r) * ldS + c0 + c];
    u16* d = &tile[r * 72 + c];
    d[0] = f2bf(v.x); d[1] = f2bf(v.y); d[2] = f2bf(v.z); d[3] = f2bf(v.w);
  }
  __syncthreads();
  #pragma unroll
  for (int i = 0; i < 2; ++i) {
    int e = i * 2048 + t * 8;
    int r2 = e >> 6, c2 = e & 63;
    u16 v[8];
    #pragma unroll
    for (int j = 0; j < 8; ++j) v[j] = tile[(c2 + j) * 72 + r2];
    *(uint4*)&dst[(size_t)(c0 + r2) * ldD + r0 + c2] = *(const uint4*)v;
  }
}

// 22x 256x256 weights -> WT[z][256][256] bf16 transposed
__global__ __launch_bounds__(256) void wprep256(
    const float* g, const float* wv, const float* wk, const float* wq,
    const float* wo, const float* wz, const float* wr, const float* w,
    const float* uz, const float* ur, const float* u, u16* WT)
{
  __shared__ u16 tile[64 * 72];
  int z = blockIdx.z, idx = z >> 1, l = z & 1;
  const float* src;
  switch (idx) {
    case 0: src = g; break;  case 1: src = wv; break; case 2: src = wk; break;
    case 3: src = wq; break; case 4: src = wo; break; case 5: src = wz; break;
    case 6: src = wr; break; case 7: src = w; break;  case 8: src = uz; break;
    case 9: src = ur; break; default: src = u; break;
  }
  src += (size_t)l * 65536;
  u16* dst = WT + (size_t)z * 65536;
  tcast_tile(src, dst, 256, 256, blockIdx.x * 64, blockIdx.y * 64, threadIdx.x, tile);
}

// fc1_w / fc2_w [1024][256] -> WTfc[z][256][1024]
__global__ __launch_bounds__(256) void wprepfc(
    const float* w1, const float* w2, u16* WTfc)
{
  __shared__ u16 tile[64 * 72];
  int z = blockIdx.z;
  const float* src = z ? w2 : w1;
  u16* dst = WTfc + (size_t)z * 262144;
  tcast_tile(src, dst, 256, 1024, blockIdx.x * 64, blockIdx.y * 64, threadIdx.x, tile);
}

// generic u16 transpose: dst[c][r] = src[r][c], 64x64 tiles
__global__ __launch_bounds__(256) void utransp_kernel(
    const u16* __restrict__ src, u16* __restrict__ dst, int ldS, int ldD)
{
  __shared__ u16 tile[64 * 72];
  int r0 = blockIdx.x * 64, c0 = blockIdx.y * 64;
  int t = threadIdx.x;
  #pragma unroll
  for (int i = 0; i < 2; ++i) {
    int e = i * 256 + t;
    int sr = e >> 3, d8 = (e & 7) * 8;
    *(uint4*)&tile[sr * 72 + d8] = *(const uint4*)&src[(size_t)(r0 + sr) * ldS + c0 + d8];
  }
  __syncthreads();
  #pragma unroll
  for (int i = 0; i < 2; ++i) {
    int e = i * 256 + t;
    int dr = e >> 3, s8 = (e & 7) * 8;
    u16 v[8];
    #pragma unroll
    for (int j = 0; j < 8; ++j) v[j] = tile[(s8 + j) * 72 + dr];
    *(uint4*)&dst[(size_t)(c0 + dr) * ldD + r0 + s8] = *(const uint4*)v;
  }
}

// out_w [256][7] -> WTout [7][256]
__global__ __launch_bounds__(256) void outprep(const float* ow, u16* WTout) {
  int t = threadIdx.x;
  for (int e = t; e < NCLS * 256; e += 256) {
    int n = e >> 8, k = e & 255;
    WTout[e] = f2bf(ow[k * NCLS + n]);
  }
}

// ======================= universal MFMA GEMM (two z-groups) =================
__device__ __forceinline__ void stage_a(const float* p, u16* d) {
  #pragma unroll
  for (int q = 0; q < 4; ++q) {
    float4 v = *(const float4*)(p + q * 4);
    d[q * 4 + 0] = f2bf(v.x); d[q * 4 + 1] = f2bf(v.y);
    d[q * 4 + 2] = f2bf(v.z); d[q * 4 + 3] = f2bf(v.w);
  }
}
__device__ __forceinline__ void stage_a(const u16* p, u16* d) {
  *(uint4*)d = *(const uint4*)p;
  *(uint4*)(d + 8) = *(const uint4*)(p + 8);
}

template <typename TA, typename TC>
__global__ __launch_bounds__(256) void gemm_t(
    const TA* __restrict__ A, const TA* __restrict__ A2, int zsplit,
    const u16* __restrict__ Wt, const u16* __restrict__ Wt2,
    const float* __restrict__ bias, const float* __restrict__ bias2,
    TC* __restrict__ C,
    int K, int ldA, int ldW, int Nc, int act,
    size_t sA, size_t sW, size_t sC)
{
  __shared__ u16 As[64 * 72];
  __shared__ u16 Ws[64 * 72];
  int z = blockIdx.z;
  const TA* Ab; const u16* Wb; const float* bs;
  if (z < zsplit) {
    Ab = A + (size_t)z * sA; Wb = Wt + (size_t)z * sW; bs = bias;
  } else {
    int z2 = z - zsplit;
    Ab = A2 + (size_t)z2 * sA; Wb = Wt2 + (size_t)z2 * sW; bs = bias2;
  }
  TC* Cb = C + (size_t)z * sC;
  int bm = blockIdx.x * 64, bn = blockIdx.y * 64;
  int t = threadIdx.x;
  int w = t >> 6, lane = t & 63, quad = lane >> 4, l15 = lane & 15;
  int wy = w >> 1, wx = w & 1;
  int sr = t >> 2, kg = (t & 3) * 16;
  bool wok = (bn + sr) < Nc;
  f32x4 acc[2][2];
  #pragma unroll
  for (int i = 0; i < 2; ++i)
    #pragma unroll
    for (int j = 0; j < 2; ++j) acc[i][j] = (f32x4){0.f, 0.f, 0.f, 0.f};

  for (int k0 = 0; k0 < K; k0 += 64) {
    u16 av[16];
    stage_a(Ab + (size_t)(bm + sr) * ldA + k0 + kg, av);
    *(uint4*)&As[sr * 72 + kg] = *(const uint4*)av;
    *(uint4*)&As[sr * 72 + kg + 8] = *(const uint4*)(av + 8);
    if (wok) {
      *(uint4*)&Ws[sr * 72 + kg] = *(const uint4*)(Wb + (size_t)(bn + sr) * ldW + k0 + kg);
      *(uint4*)&Ws[sr * 72 + kg + 8] = *(const uint4*)(Wb + (size_t)(bn + sr) * ldW + k0 + kg + 8);
    } else {
      uint4 zz = {0, 0, 0, 0};
      *(uint4*)&Ws[sr * 72 + kg] = zz;
      *(uint4*)&Ws[sr * 72 + kg + 8] = zz;
    }
    __syncthreads();
    #pragma unroll
    for (int kh = 0; kh < 64; kh += 32) {
      short8 a0 = *(const short8*)&As[(wy * 32 + l15) * 72 + kh + quad * 8];
      short8 a1 = *(const short8*)&As[(wy * 32 + 16 + l15) * 72 + kh + quad * 8];
      short8 b0 = *(const short8*)&Ws[(wx * 32 + l15) * 72 + kh + quad * 8];
      short8 b1 = *(const short8*)&Ws[(wx * 32 + 16 + l15) * 72 + kh + quad * 8];
      acc[0][0] = __builtin_amdgcn_mfma_f32_16x16x32_bf16(a0, b0, acc[0][0], 0, 0, 0);
      acc[0][1] = __builtin_amdgcn_mfma_f32_16x16x32_bf16(a0, b1, acc[0][1], 0, 0, 0);
      acc[1][0] = __builtin_amdgcn_mfma_f32_16x16x32_bf16(a1, b0, acc[1][0], 0, 0, 0);
      acc[1][1] = __builtin_amdgcn_mfma_f32_16x16x32_bf16(a1, b1, acc[1][1], 0, 0, 0);
    }
    __syncthreads();
  }
  #pragma unroll
  for (int sa = 0; sa < 2; ++sa) {
    #pragma unroll
    for (int sb = 0; sb < 2; ++sb) {
      int col = bn + wx * 32 + sb * 16 + l15;
      if (col < Nc) {
        float bv = bs ? bs[col] : 0.f;
        #pragma unroll
        for (int r = 0; r < 4; ++r) {
          int row = bm + wy * 32 + sa * 16 + quad * 4 + r;
          float v = acc[sa][sb][r] + bv;
          if (act == 1) v = fmaxf(v, 0.f);
          else if (act == 2) v = (v > 0.f) ? v : (__expf(v) - 1.f);  // elu
          stf(Cb, (size_t)row * Nc + col, v);
        }
      }
    }
  }
}

// ---- fused wo-GEMM + LayerNorm: Hn = LN(A@wo + bo + Hres) ------------------
__global__ __launch_bounds__(256) void wo_ln_kernel(
    const float* __restrict__ A, const u16* __restrict__ Wt,
    const float* __restrict__ bias, const float* __restrict__ Hres,
    const float* __restrict__ gg, const float* __restrict__ bb,
    float* __restrict__ out)
{
  __shared__ u16 As[32 * 72];
  __shared__ u16 Ws[256 * 72];
  __shared__ float red1[2][32], red2[2][32];
  int bm = blockIdx.x * 32;
  int t = threadIdx.x;
  int w = t >> 6, lane = t & 63, quad = lane >> 4, l15 = lane & 15;
  int rhalf = w & 1, chalf = w >> 1;
  f32x4 acc[8];
  #pragma unroll
  for (int nt = 0; nt < 8; ++nt) acc[nt] = (f32x4){0.f, 0.f, 0.f, 0.f};

  for (int k0 = 0; k0 < HID; k0 += 64) {
    {
      int row = t >> 3, k8 = (t & 7) * 8;
      const float* p = A + (size_t)(bm + row) * HID + k0 + k8;
      float4 v0 = *(const float4*)p;
      float4 v1 = *(const float4*)(p + 4);
      u16 d[8];
      d[0] = f2bf(v0.x); d[1] = f2bf(v0.y); d[2] = f2bf(v0.z); d[3] = f2bf(v0.w);
      d[4] = f2bf(v1.x); d[5] = f2bf(v1.y); d[6] = f2bf(v1.z); d[7] = f2bf(v1.w);
      *(uint4*)&As[row * 72 + k8] = *(const uint4*)d;
    }
    #pragma unroll
    for (int i = 0; i < 8; ++i) {
      int e = i * 256 + t;
      int n = e >> 3, k8 = (e & 7) * 8;
      *(uint4*)&Ws[n * 72 + k8] = *(const uint4*)&Wt[(size_t)n * HID + k0 + k8];
    }
    __syncthreads();
    #pragma unroll
    for (int kh = 0; kh < 64; kh += 32) {
      short8 a = *(const short8*)&As[(rhalf * 16 + l15) * 72 + kh + quad * 8];
      #pragma unroll
      for (int nt = 0; nt < 8; ++nt) {
        short8 b = *(const short8*)&Ws[(chalf * 128 + nt * 16 + l15) * 72 + kh + quad * 8];
        acc[nt] = __builtin_amdgcn_mfma_f32_16x16x32_bf16(a, b, acc[nt], 0, 0, 0);
      }
    }
    __syncthreads();
  }
  float rs1[4] = {0, 0, 0, 0}, rs2[4] = {0, 0, 0, 0};
  #pragma unroll
  for (int nt = 0; nt < 8; ++nt) {
    int col = chalf * 128 + nt * 16 + l15;
    float bv = bias[col];
    #pragma unroll
    for (int r = 0; r < 4; ++r) {
      int row = bm + rhalf * 16 + quad * 4 + r;
      float v = acc[nt][r] + bv + Hres[(size_t)row * HID + col];
      acc[nt][r] = v;
      rs1[r] += v;
      rs2[r] += v * v;
    }
  }
  #pragma unroll
  for (int off = 1; off < 16; off <<= 1) {
    #pragma unroll
    for (int r = 0; r < 4; ++r) {
      rs1[r] += __shfl_xor(rs1[r], off, 64);
      rs2[r] += __shfl_xor(rs2[r], off, 64);
    }
  }
  if (l15 == 0) {
    #pragma unroll
    for (int r = 0; r < 4; ++r) {
      red1[chalf][rhalf * 16 + quad * 4 + r] = rs1[r];
      red2[chalf][rhalf * 16 + quad * 4 + r] = rs2[r];
    }
  }
  __syncthreads();
  float mu[4], rstd[4];
  #pragma unroll
  for (int r = 0; r < 4; ++r) {
    int lr = rhalf * 16 + quad * 4 + r;
    float s1 = red1[0][lr] + red1[1][lr];
    float s2 = red2[0][lr] + red2[1][lr];
    float m = s1 * (1.f / HID);
    float var = s2 * (1.f / HID) - m * m;
    var = fmaxf(var, 0.f);
    mu[r] = m;
    rstd[r] = rsqrtf(var + 1e-5f);
  }
  #pragma unroll
  for (int nt = 0; nt < 8; ++nt) {
    int col = chalf * 128 + nt * 16 + l15;
    float g = gg[col], bbv = bb[col];
    #pragma unroll
    for (int r = 0; r < 4; ++r) {
      int row = bm + rhalf * 16 + quad * 4 + r;
      out[(size_t)row * HID + col] = (acc[nt][r] - mu[r]) * rstd[r] * g + bbv;
    }
  }
}

// -------- fc2 K-split reduce ------------------------------------------------
__global__ __launch_bounds__(256) void fc2_reduce(
    const float* __restrict__ scr, const float* __restrict__ bias,
    float* __restrict__ out)
{
  int i = blockIdx.x * 256 + threadIdx.x;
  float v = scr[i] + scr[16384 + i] + scr[32768 + i] + scr[49152 + i]
          + bias[threadIdx.x];
  out[i] = fmaxf(v, 0.f);
}

// -------- GRU combine -------------------------------------------------------
__global__ __launch_bounds__(256) void gru_combine(
    const float* __restrict__ zP, const float* __restrict__ zU,
    const float* __restrict__ P, float* __restrict__ Pn)
{
  int i = blockIdx.x * 256 + threadIdx.x;
  float z = 1.f / (1.f + __expf(-(zP[i] + zU[i])));
  float r = 1.f / (1.f + __expf(-(zP[16384 + i] + zU[16384 + i])));
  float hh = tanhf(zP[32768 + i] + r * zU[32768 + i]);
  Pn[i] = (1.f - z) * P[i] + z * hh;
}

// -------- P_l_1 batched: 8 n-rows/block, 32 lanes x 8 d per row -------------
__global__ __launch_bounds__(256) void pl1_kernel(
    const float* __restrict__ s_adj, const float* __restrict__ P,
    float* __restrict__ out)
{
  int blk = blockIdx.x;             // B*N/8 = 1024
  int b = blk >> 7;
  int n = ((blk & 127) << 3) + (threadIdx.x >> 5);
  int d0 = (threadIdx.x & 31) * 8;
  float acc[8] = {};
  #pragma unroll
  for (int m = 0; m < MSP; ++m) {
    float sa = s_adj[(size_t)(b * MSP + m) * N + n];
    const float* Pp = &P[(size_t)(b * MSP + m) * HID + d0];
    float4 p0 = *(const float4*)Pp;
    float4 p1 = *(const float4*)(Pp + 4);
    acc[0] += sa * p0.x; acc[1] += sa * p0.y; acc[2] += sa * p0.z; acc[3] += sa * p0.w;
    acc[4] += sa * p1.x; acc[5] += sa * p1.y; acc[6] += sa * p1.z; acc[7] += sa * p1.w;
  }
  float* op = &out[(size_t)(b * N + n) * HID + d0];
  *(float4*)op = (float4){acc[0], acc[1], acc[2], acc[3]};
  *(float4*)(op + 4) = (float4){acc[4], acc[5], acc[6], acc[7]};
}

// -------- rel_sc (both layers, once) ----------------------------------------
__global__ __launch_bounds__(256) void relsc_kernel(
    const float* __restrict__ rel_emb, const float* __restrict__ gat_a,
    float* __restrict__ rsc)
{
  __shared__ float scratch[4];
  int z = blockIdx.x, l = z >> 1, r = z & 1, t = threadIdx.x;
  const float* re = rel_emb + ((size_t)l * 2 + r) * HID;
  const float* a3 = gat_a + (size_t)l * 3 * HID + 2 * HID;
  float v = re[t] * a3[t];
  int wave = t >> 6, lane = t & 63;
  v = wave_reduce_sum(v);
  if (lane == 0) scratch[wave] = v;
  __syncthreads();
  if (t == 0) rsc[z] = scratch[0] + scratch[1] + scratch[2] + scratch[3];
}

// -------- f1/f2 batched: 8 rows/block ---------------------------------------
__global__ __launch_bounds__(256) void f1f2_kernel(
    const u16* __restrict__ h, const float* __restrict__ a12,
    float* __restrict__ f1, float* __restrict__ f2)
{
  int row0 = blockIdx.x * 8;
  int t = threadIdx.x;
  int r = t >> 5;
  int c0 = (t & 31) * 8;
  const u16* hp = &h[(size_t)(row0 + r) * HID + c0];
  uint4 raw = *(const uint4*)hp;
  const u16* hv16 = (const u16*)&raw;
  float v1 = 0.f, v2 = 0.f;
  #pragma unroll
  for (int j = 0; j < 8; ++j) {
    float hv = bf2f(hv16[j]);
    v1 += hv * a12[c0 + j];
    v2 += hv * a12[HID + c0 + j];
  }
  #pragma unroll
  for (int off = 1; off < 32; off <<= 1) {
    v1 += __shfl_xor(v1, off, 32);
    v2 += __shfl_xor(v2, off, 32);
  }
  if ((t & 31) == 0) {
    f1[row0 + r] = v1;
    f2[row0 + r] = v2;
  }
}

// -------- RGAT scores (register-resident) -----------------------------------
__global__ __launch_bounds__(256) void rgat_scores_kernel(
    const int* __restrict__ adj, const int* __restrict__ smask,
    const float* __restrict__ f1, const float* __restrict__ f2,
    const float* __restrict__ rsc, u16* __restrict__ Pw)
{
  __shared__ float red[4][RROWS];
  int blk = blockIdx.x;
  int b = blk / (N / RROWS);
  int i0 = (blk % (N / RROWS)) * RROWS;
  int t = threadIdx.x;
  int wave = t >> 6, lane = t & 63;
  float r0 = rsc[0], r1 = rsc[1];
  int j0 = t * 4;
  float4 f2v = *(const float4*)&f2[b * N + j0];
  float ev[RROWS][4];
  #pragma unroll
  for (int r = 0; r < RROWS; ++r) {
    size_t base = ((size_t)(b * N + i0 + r)) * N + j0;
    int4 a4 = *(const int4*)&adj[base];
    int4 s4 = *(const int4*)&smask[base];
    float f1v = f1[b * N + i0 + r];
    float e;
    e = f1v + f2v.x + (s4.x ? r1 : r0); e = (e > 0.f) ? e : LALPHA * e;
    ev[r][0] = (a4.x > 0) ? e : NEGF;
    e = f1v + f2v.y + (s4.y ? r1 : r0); e = (e > 0.f) ? e : LALPHA * e;
    ev[r][1] = (a4.y > 0) ? e : NEGF;
    e = f1v + f2v.z + (s4.z ? r1 : r0); e = (e > 0.f) ? e : LALPHA * e;
    ev[r][2] = (a4.z > 0) ? e : NEGF;
    e = f1v + f2v.w + (s4.w ? r1 : r0); e = (e > 0.f) ? e : LALPHA * e;
    ev[r][3] = (a4.w > 0) ? e : NEGF;
  }
  #pragma unroll
  for (int r = 0; r < RROWS; ++r) {
    float m = fmaxf(fmaxf(ev[r][0], ev[r][1]), fmaxf(ev[r][2], ev[r][3]));
    m = wave_reduce_max(m);
    if (lane == 0) red[wave][r] = m;
  }
  __syncthreads();
  float mx[RROWS];
  #pragma unroll
  for (int r = 0; r < RROWS; ++r)
    mx[r] = fmaxf(fmaxf(red[0][r], red[1][r]), fmaxf(red[2][r], red[3][r]));
  __syncthreads();
  #pragma unroll
  for (int r = 0; r < RROWS; ++r) {
    float s = 0.f;
    #pragma unroll
    for (int c = 0; c < 4; ++c) { ev[r][c] = __expf(ev[r][c] - mx[r]); s += ev[r][c]; }
    s = wave_reduce_sum(s);
    if (lane == 0) red[wave][r] = s;
  }
  __syncthreads();
  #pragma unroll
  for (int r = 0; r < RROWS; ++r) {
    float inv = 1.f / (red[0][r] + red[1][r] + red[2][r] + red[3][r]);
    u16 o[4];
    #pragma unroll
    for (int c = 0; c < 4; ++c) o[c] = f2bf(ev[r][c] * inv);
    *(uint2*)&Pw[((size_t)(b * N + i0 + r)) * N + j0] = *(const uint2*)o;
  }
}

// -------- bf16 transpose: Vt[g][d][s] = V[g][s][d] --------------------------
__global__ __launch_bounds__(256) void vtransp_kernel(
    const u16* __restrict__ Vb, u16* __restrict__ Vt)
{
  __shared__ u16 tile[64 * 72];
  int g = blockIdx.x & 31;
  int s0 = (blockIdx.x >> 5) * 64;
  int t = threadIdx.x;
  #pragma unroll
  for (int i = 0; i < 2; ++i) {
    int e = i * 256 + t;
    int sr = e >> 3, d8 = (e & 7) * 8;
    *(uint4*)&tile[sr * 72 + d8] =
        *(const uint4*)&Vb[((size_t)(g * SEQ) + s0 + sr) * DHD + d8];
  }
  __syncthreads();
  #pragma unroll
  for (int i = 0; i < 2; ++i) {
    int e = i * 256 + t;
    int dr = e >> 3, s8 = (e & 7) * 8;
    u16 v[8];
    #pragma unroll
    for (int j = 0; j < 8; ++j) v[j] = tile[(s8 + j) * 72 + dr];
    *(uint4*)&Vt[((size_t)(g * DHD) + dr) * SEQ + s0 + s8] = *(const uint4*)v;
  }
}

// -------- MFMA flash MHA: 64-key chunks, XCD swizzle, LDS double-buffer -----
__global__ __launch_bounds__(256) void mha_mfma_kernel(
    const u16* __restrict__ Qb, const u16* __restrict__ Kb,
    const u16* __restrict__ Vt, float* __restrict__ ctx)
{
  __shared__ u16 Ks[2][64 * 72];
  __shared__ u16 Vs[2][64 * 72];
  __shared__ u16 Ps[4][16 * 72];
  int g = blockIdx.x & 31;
  int q0 = (blockIdx.x >> 5) * 64;
  int t = threadIdx.x;
  int w = t >> 6, lane = t & 63, quad = lane >> 4, l15 = lane & 15;
  const u16* Qrow = Qb + ((size_t)(g * SEQ) + q0 + w * 16 + l15) * DHD;
  short8 qa0 = *(const short8*)(Qrow + quad * 8);
  short8 qa1 = *(const short8*)(Qrow + 32 + quad * 8);
  const u16* Kg = Kb + (size_t)g * SEQ * DHD;
  const u16* Vg = Vt + (size_t)g * DHD * SEQ;
  int srow = t >> 3, sc8 = (t & 7) * 8;
  int srow1 = (256 + t) >> 3;
  f32x4 O[4];
  #pragma unroll
  for (int nt = 0; nt < 4; ++nt) O[nt] = (f32x4){0.f, 0.f, 0.f, 0.f};
  float mprev[4] = {-1e30f, -1e30f, -1e30f, -1e30f};
  float lsum[4] = {0.f, 0.f, 0.f, 0.f};

  *(uint4*)&Ks[0][srow * 72 + sc8] = *(const uint4*)&Kg[(size_t)srow * DHD + sc8];
  *(uint4*)&Ks[0][srow1 * 72 + sc8] = *(const uint4*)&Kg[(size_t)srow1 * DHD + sc8];
  *(uint4*)&Vs[0][srow * 72 + sc8] = *(const uint4*)&Vg[(size_t)srow * SEQ + sc8];
  *(uint4*)&Vs[0][srow1 * 72 + sc8] = *(const uint4*)&Vg[(size_t)srow1 * SEQ + sc8];

  int ping = 0;
  for (int kc = 0; kc < SEQ; kc += 64) {
    __syncthreads();
    if (kc + 64 < SEQ) {
      int pn = 1 - ping, kn = kc + 64;
      *(uint4*)&Ks[pn][srow * 72 + sc8] = *(const uint4*)&Kg[(size_t)(kn + srow) * DHD + sc8];
      *(uint4*)&Ks[pn][srow1 * 72 + sc8] = *(const uint4*)&Kg[(size_t)(kn + srow1) * DHD + sc8];
      *(uint4*)&Vs[pn][srow * 72 + sc8] = *(const uint4*)&Vg[(size_t)srow * SEQ + kn + sc8];
      *(uint4*)&Vs[pn][srow1 * 72 + sc8] = *(const uint4*)&Vg[(size_t)srow1 * SEQ + kn + sc8];
    }
    f32x4 s[4];
    #pragma unroll
    for (int st = 0; st < 4; ++st) {
      short8 b0 = *(const short8*)&Ks[ping][(st * 16 + l15) * 72 + quad * 8];
      short8 b1 = *(const short8*)&Ks[ping][(st * 16 + l15) * 72 + 32 + quad * 8];
      f32x4 c = (f32x4){0.f, 0.f, 0.f, 0.f};
      c = __builtin_amdgcn_mfma_f32_16x16x32_bf16(qa0, b0, c, 0, 0, 0);
      c = __builtin_amdgcn_mfma_f32_16x16x32_bf16(qa1, b1, c, 0, 0, 0);
      s[st] = c * 0.125f;
    }
    float cm[4];
    #pragma unroll
    for (int r = 0; r < 4; ++r)
      cm[r] = fmaxf(fmaxf(s[0][r], s[1][r]), fmaxf(s[2][r], s[3][r]));
    #pragma unroll
    for (int off = 1; off < 16; off <<= 1) {
      #pragma unroll
      for (int r = 0; r < 4; ++r) cm[r] = fmaxf(cm[r], __shfl_xor(cm[r], off, 64));
    }
    float mnew[4], alpha[4], rs[4];
    #pragma unroll
    for (int r = 0; r < 4; ++r) {
      mnew[r] = fmaxf(mprev[r], cm[r]);
      alpha[r] = __expf(mprev[r] - mnew[r]);
      mprev[r] = mnew[r];
      rs[r] = 0.f;
    }
    #pragma unroll
    for (int st = 0; st < 4; ++st) {
      #pragma unroll
      for (int r = 0; r < 4; ++r) {
        float p = __expf(s[st][r] - mnew[r]);
        rs[r] += p;
        Ps[w][(quad * 4 + r) * 72 + st * 16 + l15] = f2bf(p);
      }
    }
    #pragma unroll
    for (int off = 1; off < 16; off <<= 1) {
      #pragma unroll
      for (int r = 0; r < 4; ++r) rs[r] += __shfl_xor(rs[r], off, 64);
    }
    #pragma unroll
    for (int r = 0; r < 4; ++r) lsum[r] = lsum[r] * alpha[r] + rs[r];
    #pragma unroll
    for (int nt = 0; nt < 4; ++nt)
      #pragma unroll
      for (int r = 0; r < 4; ++r) O[nt][r] *= alpha[r];
    #pragma unroll
    for (int kh = 0; kh < 2; ++kh) {
      short8 pa = *(const short8*)&Ps[w][l15 * 72 + kh * 32 + quad * 8];
      #pragma unroll
      for (int nt = 0; nt < 4; ++nt) {
        short8 vb = *(const short8*)&Vs[ping][(nt * 16 + l15) * 72 + kh * 32 + quad * 8];
        O[nt] = __builtin_amdgcn_mfma_f32_16x16x32_bf16(pa, vb, O[nt], 0, 0, 0);
      }
    }
    ping ^= 1;
  }
  #pragma unroll
  for (int nt = 0; nt < 4; ++nt) {
    #pragma unroll
    for (int r = 0; r < 4; ++r) {
      size_t row = (size_t)(g * SEQ) + q0 + w * 16 + quad * 4 + r;
      ctx[row * DHD + nt * 16 + l15] = O[nt][r] / lsum[r];
    }
  }
}

// -------- P_agg split-n: part + reduce --------------------------------------
__global__ __launch_bounds__(256) void pagg_part(
    const float* __restrict__ s_adj, const float* __restrict__ H,
    float* __restrict__ scr)
{
  int row = blockIdx.x;
  int sl = blockIdx.y;
  int b = row >> 3, t = threadIdx.x;
  const float* Hb = H + ((size_t)(b * N) + sl * 128) * HID + t;
  const float* sa = s_adj + (size_t)row * N + sl * 128;
  float acc = 0.f;
  #pragma unroll 4
  for (int n = 0; n < 128; ++n)
    acc += sa[n] * Hb[(size_t)n * HID];
  scr[((size_t)sl * (B * MSP) + row) * HID + t] = acc;
}
__global__ __launch_bounds__(256) void pagg_reduce(
    const float* __restrict__ scr, float* __restrict__ Pagg)
{
  int row = blockIdx.x, t = threadIdx.x;
  float s = 0.f;
  #pragma unroll
  for (int k = 0; k < 8; ++k) s += scr[((size_t)k * (B * MSP) + row) * HID + t];
  Pagg[(size_t)row * HID + t] = s;
}

// -------- p_sim -------------------------------------------------------------
__global__ __launch_bounds__(256) void psim_kernel(
    const float* __restrict__ P, float* __restrict__ out)
{
  __shared__ float scratch[4];
  int t = threadIdx.x;
  float total = 0.f;
  for (int idx = t; idx < B * MSP * MSP; idx += 256) {
    int b = idx >> 6, m = (idx >> 3) & 7, k = idx & 7;
    if (m != k) {
      const float* pm = P + (size_t)(b * MSP + m) * HID;
      const float* pk = P + (size_t)(b * MSP + k) * HID;
      float d = 0.f;
      for (int dd = 0; dd < HID; ++dd) d += pm[dd] * pk[dd];
      total += d;
    }
  }
  int wave = t >> 6, lane = t & 63;
  total = wave_reduce_sum(total);
  if (lane == 0) scratch[wave] = total;
  __syncthreads();
  if (t == 0)
    out[0] = (scratch[0] + scratch[1] + scratch[2] + scratch[3]) *
             (1.f / (B * MSP * MSP));
}

extern "C" void kernel_launch(void* const* d_in, const int* in_sizes, int n_in,
                              void* d_out, int out_size, void* d_ws, size_t ws_size,
                              hipStream_t stream) {
  const float* x      = (const float*)d_in[0];
  const int*   adj    = (const int*)d_in[1];
  const int*   smask  = (const int*)d_in[2];
  const float* s_feat = (const float*)d_in[3];
  const float* s_adj  = (const float*)d_in[4];
  const float* fc1_w  = (const float*)d_in[6];
  const float* fc1_b  = (const float*)d_in[7];
  const float* fc2_w  = (const float*)d_in[8];
  const float* fc2_b  = (const float*)d_in[9];
  const float* gat_W  = (const float*)d_in[10];
  const float* gat_a  = (const float*)d_in[11];
  const float* rel_emb= (const float*)d_in[12];
  const float* gru_wz = (const float*)d_in[13];
  const float* gru_uz = (const float*)d_in[14];
  const float* gru_wr = (const float*)d_in[15];
  const float* gru_ur = (const float*)d_in[16];
  const float* gru_w  = (const float*)d_in[17];
  const float* gru_u  = (const float*)d_in[18];
  const float* mha_wv = (const float*)d_in[19];
  const float* mha_bv = (const float*)d_in[20];
  const float* mha_wk = (const float*)d_in[21];
  const float* mha_bk = (const float*)d_in[22];
  const float* mha_wq = (const float*)d_in[23];
  const float* mha_bq = (const float*)d_in[24];
  const float* mha_wo = (const float*)d_in[25];
  const float* mha_bo = (const float*)d_in[26];
  const float* ln_g   = (const float*)d_in[27];
  const float* ln_b   = (const float*)d_in[28];
  const float* out_w  = (const float*)d_in[29];
  const float* out_b  = (const float*)d_in[30];

  float* ws = (float*)d_ws;
  const size_t BIG = (size_t)B * N * HID;   // 2,097,152 floats (8 MB)
  float* H0  = ws + 0 * BIG;
  float* H1  = ws + 1 * BIG;
  u16* hb16 = (u16*)(ws + 2 * BIG);
  u16* Vb16 = hb16 + BIG;
  float* Pl1 = ws + 3 * BIG;          // P_l_1; GRU/pagg scratch after QK gemm
  float* Agg = ws + 4 * BIG;
  u16* Pw   = (u16*)(ws + 5 * BIG);
  u16* Qb16 = (u16*)(ws + 5 * BIG);
  u16* Kb16 = Qb16 + BIG;
  u16* Vt16 = (u16*)(ws + 6 * BIG);
  u16* ht   = (u16*)(ws + 7 * BIG);
  u16* WT   = ht + 2097152;
  u16* WTfc = WT + 22 * 65536;
  u16* WTout= WTfc + 2 * 262144;
  float* scrFc = Agg;
  float* zP = Pl1;
  float* zU = Pl1 + 3 * 16384;
  float* paggScr = Pl1 + 6 * 16384;
  float* smw = ws + 8 * BIG;
  float* P0   = smw;
  float* P1   = smw + 16384;
  float* Pagg = smw + 32768;
  float* f1   = smw + 49152;
  float* f2   = smw + 57344;
  float* rsc4 = smw + 65536;

  dim3 blk(256);
  const size_t W64K = 65536;

  wprep256<<<dim3(4, 4, 22), blk, 0, stream>>>(
      gat_W, mha_wv, mha_wk, mha_wq, mha_wo,
      gru_wz, gru_wr, gru_w, gru_uz, gru_ur, gru_u, WT);
  wprepfc<<<dim3(16, 4, 2), blk, 0, stream>>>(fc1_w, fc2_w, WTfc);
  outprep<<<1, blk, 0, stream>>>(out_w, WTout);
  relsc_kernel<<<4, blk, 0, stream>>>(rel_emb, gat_a, rsc4);

  gemm_t<float, float><<<dim3(128, 4, 1), blk, 0, stream>>>(
      x, x, 99, WTfc, WTfc, fc1_b, fc1_b, H0, DIN, DIN, DIN, HID, 1, 0, 0, 0);
  gemm_t<float, float><<<dim3(1, 4, 4), blk, 0, stream>>>(
      s_feat, s_feat, 99, WTfc + 262144, WTfc, nullptr, nullptr, scrFc,
      256, DIN, DIN, HID, 0, 256, 256, 16384);
  fc2_reduce<<<64, blk, 0, stream>>>(scrFc, fc2_b, P0);

  float* Hc = H0; float* Hn = H1; float* Pc = P0; float* Pn = P1;
  for (int l = 0; l < NLAYER; ++l) {
    pl1_kernel<<<B * N / 8, blk, 0, stream>>>(s_adj, Pc, Pl1);
    gemm_t<float, u16><<<dim3(128, 4, 2), blk, 0, stream>>>(
        Hc, Hc, 1, WT + (size_t)(0 + l) * W64K, WT + (size_t)(2 + l) * W64K,
        nullptr, mha_bv + l * HID, hb16, HID, HID, HID, HID, 0, 0, 0, BIG);
    utransp_kernel<<<dim3(128, 4), blk, 0, stream>>>(hb16, ht, HID, B * N);
    f1f2_kernel<<<B * N / 8, blk, 0, stream>>>(hb16, gat_a + (size_t)l * 3 * HID, f1, f2);
    rgat_scores_kernel<<<B * (N / RROWS), blk, 0, stream>>>(adj, smask, f1, f2,
                                                           rsc4 + l * 2, Pw);
    gemm_t<u16, float><<<dim3(16, 4, 8), blk, 0, stream>>>(
        Pw, Pw, 99, ht, ht, nullptr, nullptr, Agg, N, N, B * N, HID, 2,
        (size_t)N * N, (size_t)N, (size_t)N * HID);
    gemm_t<float, u16><<<dim3(128, 4, 2), blk, 0, stream>>>(
        Agg, Pl1, 1, WT + (size_t)(6 + l) * W64K, WT + (size_t)(4 + l) * W64K,
        mha_bq + l * HID, mha_bk + l * HID, Qb16, HID, HID, HID, HID, 0, 0, 0, BIG);
    vtransp_kernel<<<G * (SEQ / 64), blk, 0, stream>>>(Vb16, Vt16);
    mha_mfma_kernel<<<G * (SEQ / 64), blk, 0, stream>>>(Qb16, Kb16, Vt16, Agg);
    wo_ln_kernel<<<B * N / 32, blk, 0, stream>>>(
        Agg, WT + (size_t)(8 + l) * W64K, mha_bo + l * HID, Hc,
        ln_g + l * HID, ln_b + l * HID, Hn);
    pagg_part<<<dim3(B * MSP, 8), blk, 0, stream>>>(s_adj, Hc, paggScr);
    pagg_reduce<<<B * MSP, blk, 0, stream>>>(paggScr, Pagg);
    gemm_t<float, float><<<dim3(1, 4, 6), blk, 0, stream>>>(
        Pc, Pagg, 3, WT + (size_t)(10 + l) * W64K, WT + (size_t)(16 + l) * W64K,
        nullptr, nullptr, zP, HID, HID, HID, HID, 0, 0, 2 * W64K, 16384);
    gru_combine<<<64, blk, 0, stream>>>(zP, zU, Pc, Pn);
    float* th = Hc; Hc = Hn; Hn = th;
    float* tp = Pc; Pc = Pn; Pn = tp;
  }
  gemm_t<float, float><<<dim3(128, 1, 1), blk, 0, stream>>>(
      Hc, Hc, 99, WTout, WTout, out_b, out_b, (float*)d_out,
      HID, HID, HID, NCLS, 0, 0, 0, 0);
  psim_kernel<<<1, blk, 0, stream>>>(Pc, (float*)d_out + (size_t)B * N * NCLS);
}